// Round 6
// baseline (128.569 us; speedup 1.0000x reference)
//
#include <hip/hip_runtime.h>

#define N_NODES 50000
#define N_EDGES 300000
#define D_FEAT 256
// Live computation (sage1/sage2 outputs are dead in the reference):
// h = relu(mean_agg(x)@Wl3 + x@Wr3 + b3)
// out = log_softmax(mean_agg(h)@Wl4 + h@Wr4 + b4)
// Project first (256->32 via bf16 MFMA), aggregate in 32-dim space via
// edge-parallel f32 atomics (measured faster than CSR build + gather).
// 6 kernels.

typedef __attribute__((ext_vector_type(8))) short bf16x8;
typedef __attribute__((ext_vector_type(4))) float f32x4;

#define NZERO (N_NODES * 65)   // cnt(1) + agg3(32) + agg4(32) floats, contiguous

__device__ __forceinline__ unsigned short f2bf(float f) {
    unsigned int u = __builtin_bit_cast(unsigned int, f);
    u += 0x7fffu + ((u >> 16) & 1u);   // round-to-nearest-even
    return (unsigned short)(u >> 16);
}

// pack two f32 -> one dword of 2 bf16 (RNE)
__device__ __forceinline__ unsigned cvt2bf(float lo, float hi) {
    unsigned r;
    asm("v_cvt_pk_bf16_f32 %0, %1, %2" : "=v"(r) : "v"(lo), "v"(hi));
    return r;
}

// K1: zero cnt+agg3+agg4 (13 MB) + pack [Wl3|Wr3] into bf16 B-fragment order.
// bp[((nt*8+ks)*64+lane)*8 + j] = W(k = ks*32+(lane>>4)*8+j, c = nt*16+(lane&15))
__global__ __launch_bounds__(256) void zero_wpack(const float* __restrict__ Wl,
        const float* __restrict__ Wr, unsigned short* __restrict__ bp,
        float* __restrict__ zbase) {
    int g = blockIdx.x * 256 + threadIdx.x;
    if (g < NZERO / 4)
        ((float4*)zbase)[g] = make_float4(0.f, 0.f, 0.f, 0.f);
    if (g < 2048) {
        int lane = g & 63;
        int ks = (g >> 6) & 7;
        int nt = g >> 9;
        int c = nt * 16 + (lane & 15);
        int kbase = ks * 32 + (lane >> 4) * 8;
        unsigned short o[8];
#pragma unroll
        for (int j = 0; j < 8; ++j) {
            int k = kbase + j;
            float v = (c < 32) ? Wl[k * 32 + c] : Wr[k * 32 + (c - 32)];
            o[j] = f2bf(v);
        }
        uint4 pk;
        pk.x = (unsigned)o[0] | ((unsigned)o[1] << 16);
        pk.y = (unsigned)o[2] | ((unsigned)o[3] << 16);
        pk.z = (unsigned)o[4] | ((unsigned)o[5] << 16);
        pk.w = (unsigned)o[6] | ((unsigned)o[7] << 16);
        ((uint4*)bp)[g] = pk;
    }
}

// K2: xl = x @ Wl3, xr = x @ Wr3 via bf16 MFMA; 4 waves/block, 16 rows/wave.
__global__ __launch_bounds__(256) void proj3_mfma(const float* __restrict__ x,
        const unsigned short* __restrict__ bp,
        float* __restrict__ xl, float* __restrict__ xr) {
    const int lane = threadIdx.x & 63;
    const int wv = threadIdx.x >> 6;
    const int row0 = blockIdx.x * 64 + wv * 16;
    const int arow = row0 + (lane & 15);
    const int kq = lane >> 4;
    const bool valid = arow < N_NODES;

    bf16x8 a[8];
    const float* xp = x + (size_t)arow * D_FEAT + kq * 8;
#pragma unroll
    for (int ks = 0; ks < 8; ++ks) {
        float4 p0, p1;
        if (valid) {
            p0 = *(const float4*)(xp + ks * 32);
            p1 = *(const float4*)(xp + ks * 32 + 4);
        } else {
            p0 = make_float4(0.f, 0.f, 0.f, 0.f);
            p1 = p0;
        }
        uint4 au;
        au.x = cvt2bf(p0.x, p0.y);
        au.y = cvt2bf(p0.z, p0.w);
        au.z = cvt2bf(p1.x, p1.y);
        au.w = cvt2bf(p1.z, p1.w);
        a[ks] = __builtin_bit_cast(bf16x8, au);
    }

    f32x4 acc[4];
#pragma unroll
    for (int nt = 0; nt < 4; ++nt) acc[nt] = (f32x4){0.f, 0.f, 0.f, 0.f};

    const uint4* bq = (const uint4*)bp;
#pragma unroll
    for (int nt = 0; nt < 4; ++nt) {
#pragma unroll
        for (int ks = 0; ks < 8; ++ks) {
            bf16x8 b = __builtin_bit_cast(bf16x8, bq[(nt * 8 + ks) * 64 + lane]);
            acc[nt] = __builtin_amdgcn_mfma_f32_16x16x32_bf16(a[ks], b, acc[nt], 0, 0, 0);
        }
    }

    // C/D: col = lane&15, row = (lane>>4)*4 + reg
    const int orow = row0 + (lane >> 4) * 4;
    const int ocol = lane & 15;
#pragma unroll
    for (int nt = 0; nt < 4; ++nt) {
        float* dst = (nt < 2) ? xl : xr;
        const int cc = (nt & 1) * 16 + ocol;
#pragma unroll
        for (int i = 0; i < 4; ++i) {
            int r = orow + i;
            if (r < N_NODES) dst[(size_t)r * 32 + cc] = acc[nt][i];
        }
    }
}

// K3: agg3[d][c] += xl[s][c]; lane 0 of each edge-group counts in-degree.
__global__ __launch_bounds__(256) void scatter3(const int* __restrict__ ei,
        const float* __restrict__ xl, float* __restrict__ agg3,
        float* __restrict__ cnt) {
    int gid = blockIdx.x * 256 + threadIdx.x;
    if (gid >= N_EDGES * 32) return;
    int e = gid >> 5, c = gid & 31;
    int s = ei[e], d = ei[N_EDGES + e];
    atomicAdd(&agg3[(size_t)d * 32 + c], xl[(size_t)s * 32 + c]);
    if (c == 0) atomicAdd(&cnt[d], 1.0f);
}

// K4: h = relu(agg3/cnt + xr + b3), one float4 per thread
__global__ __launch_bounds__(256) void h_kernel(const float* __restrict__ agg3,
        const float* __restrict__ xr, const float* __restrict__ cnt,
        const float* __restrict__ b3, float* __restrict__ h) {
    int gid = blockIdx.x * 256 + threadIdx.x;
    if (gid >= N_NODES * 8) return;
    int node = gid >> 3, q = gid & 7;
    float inv = 1.0f / fmaxf(cnt[node], 1.0f);
    float4 a = ((const float4*)agg3)[gid];
    float4 b = ((const float4*)xr)[gid];
    float4 bb = ((const float4*)b3)[q];
    float4 r;
    r.x = fmaxf(fmaf(a.x, inv, b.x + bb.x), 0.0f);
    r.y = fmaxf(fmaf(a.y, inv, b.y + bb.y), 0.0f);
    r.z = fmaxf(fmaf(a.z, inv, b.z + bb.z), 0.0f);
    r.w = fmaxf(fmaf(a.w, inv, b.w + bb.w), 0.0f);
    ((float4*)h)[gid] = r;
}

// K5: agg4[d][c] += h[s][c]
__global__ __launch_bounds__(256) void scatter4(const int* __restrict__ ei,
        const float* __restrict__ h, float* __restrict__ agg4) {
    int gid = blockIdx.x * 256 + threadIdx.x;
    if (gid >= N_EDGES * 32) return;
    int e = gid >> 5, c = gid & 31;
    int s = ei[e], d = ei[N_EDGES + e];
    atomicAdd(&agg4[(size_t)d * 32 + c], h[(size_t)s * 32 + c]);
}

// K6: out = log_softmax((agg4/cnt)@Wl4 + h@Wr4 + b4); 8 lanes/node x 5 cols.
__global__ __launch_bounds__(256) void out8_kernel(const float* __restrict__ agg4,
        const float* __restrict__ h, const float* __restrict__ cnt,
        const float* __restrict__ Wl4, const float* __restrict__ Wr4,
        const float* __restrict__ b4, float* __restrict__ out) {
    __shared__ float w[32][80];
    const int tid = threadIdx.x;
    for (int i = tid; i < 32 * 80; i += 256) {
        int k = i / 80, c = i - k * 80;
        w[k][c] = (c < 40) ? Wl4[k * 40 + c] : Wr4[k * 40 + (c - 40)];
    }
    __syncthreads();
    const int gid = blockIdx.x * 256 + tid;
    const int node = gid >> 3, q = gid & 7;
    if (node >= N_NODES) return;
    const float inv = 1.0f / fmaxf(cnt[node], 1.0f);
    const int c0 = q * 5;
    float acc[5];
#pragma unroll
    for (int c = 0; c < 5; ++c) acc[c] = b4[c0 + c];
    const float4* ap = (const float4*)(agg4 + (size_t)node * 32);
    const float4* hp = (const float4*)(h + (size_t)node * 32);
#pragma unroll
    for (int kq = 0; kq < 8; ++kq) {
        float4 av = ap[kq];
        float4 hv = hp[kq];
        float mk[4] = {av.x * inv, av.y * inv, av.z * inv, av.w * inv};
        float hk[4] = {hv.x, hv.y, hv.z, hv.w};
#pragma unroll
        for (int j = 0; j < 4; ++j) {
            const int k = kq * 4 + j;
#pragma unroll
            for (int c = 0; c < 5; ++c)
                acc[c] += mk[j] * w[k][c0 + c] + hk[j] * w[k][40 + c0 + c];
        }
    }
    float m = acc[0];
#pragma unroll
    for (int c = 1; c < 5; ++c) m = fmaxf(m, acc[c]);
#pragma unroll
    for (int off = 1; off < 8; off <<= 1) m = fmaxf(m, __shfl_xor(m, off, 8));
    float s = 0.0f;
#pragma unroll
    for (int c = 0; c < 5; ++c) s += expf(acc[c] - m);
#pragma unroll
    for (int off = 1; off < 8; off <<= 1) s += __shfl_xor(s, off, 8);
    const float ls = logf(s) + m;
    float* op = out + (size_t)node * 40 + c0;
#pragma unroll
    for (int c = 0; c < 5; ++c) op[c] = acc[c] - ls;
}

extern "C" void kernel_launch(void* const* d_in, const int* in_sizes, int n_in,
                              void* d_out, int out_size, void* d_ws, size_t ws_size,
                              hipStream_t stream) {
    const float* x   = (const float*)d_in[0];
    const int*   ei  = (const int*)d_in[1];
    const float* Wl3 = (const float*)d_in[8];
    const float* Wr3 = (const float*)d_in[9];
    const float* b3  = (const float*)d_in[10];
    const float* Wl4 = (const float*)d_in[11];
    const float* Wr4 = (const float*)d_in[12];
    const float* b4  = (const float*)d_in[13];
    float* outf = (float*)d_out;

    char* p = (char*)d_ws;
    float* cnt  = (float*)p;   p += sizeof(float) * N_NODES;                 // zeroed
    float* agg3 = (float*)p;   p += sizeof(float) * (size_t)N_NODES * 32;    // zeroed
    float* agg4 = (float*)p;   p += sizeof(float) * (size_t)N_NODES * 32;    // zeroed
    float* xl   = (float*)p;   p += sizeof(float) * (size_t)N_NODES * 32;
    float* xr   = (float*)p;   p += sizeof(float) * (size_t)N_NODES * 32;
    float* h    = (float*)p;   p += sizeof(float) * (size_t)N_NODES * 32;
    unsigned short* bpack = (unsigned short*)p;   // 16384 ushorts

    zero_wpack<<<(NZERO / 4 + 255) / 256, 256, 0, stream>>>(Wl3, Wr3, bpack, cnt);
    proj3_mfma<<<(N_NODES + 63) / 64, 256, 0, stream>>>(x, bpack, xl, xr);
    scatter3<<<(N_EDGES * 32 + 255) / 256, 256, 0, stream>>>(ei, xl, agg3, cnt);
    h_kernel<<<(N_NODES * 8 + 255) / 256, 256, 0, stream>>>(agg3, xr, cnt, b3, h);
    scatter4<<<(N_EDGES * 32 + 255) / 256, 256, 0, stream>>>(ei, h, agg4);
    out8_kernel<<<(N_NODES * 8 + 255) / 256, 256, 0, stream>>>(agg4, h, cnt, Wl4, Wr4, b4, outf);
}